// Round 4
// baseline (408.009 us; speedup 1.0000x reference)
//
#include <hip/hip_runtime.h>

#define N_NODES 100000
#define F_IN    256
#define H_DIM   128
#define C_DIM   64
#define E_EDGES 1600000
#define EP_EDGES 500000

#define NBUK 391          // buckets of 256 nodes: bucket = dst >> 8
#define EPB  4096         // edges per bucket-pass block

typedef unsigned short bf16_t;
typedef short  short8  __attribute__((ext_vector_type(8)));
typedef float  float4v __attribute__((ext_vector_type(4)));
typedef _Float16 half8v __attribute__((ext_vector_type(8)));

__device__ inline bf16_t f2bf(float f) {          // round-to-nearest-even
    unsigned u = __float_as_uint(f);
    u += 0x7fff + ((u >> 16) & 1);
    return (bf16_t)(u >> 16);
}
__device__ inline float bf2f(bf16_t h) {
    return __uint_as_float(((unsigned)h) << 16);
}
__device__ inline void split8(const float* vv, short* h, short* l) {
#pragma unroll
    for (int j = 0; j < 8; ++j) {
        bf16_t hb = f2bf(vv[j]);
        h[j] = (short)hb;
        l[j] = (short)f2bf(vv[j] - bf2f(hb));
    }
}
__device__ inline float4v mfma16(short8 a, short8 b, float4v c) {
    return __builtin_amdgcn_mfma_f32_16x16x32_bf16(a, b, c, 0, 0, 0);
}

// ---------------------------------------------------------------------------
// CSR build v2: bucket hist -> bucket scan -> bucket scatter -> bucket sort
// ---------------------------------------------------------------------------
__global__ __launch_bounds__(256) void bhist_kernel(const int* __restrict__ dst,
                                                    int* __restrict__ bsize) {
    __shared__ int hist[NBUK];
    const int t = threadIdx.x;
    for (int b = t; b < NBUK; b += 256) hist[b] = 0;
    __syncthreads();
    const int e0 = blockIdx.x * EPB;
#pragma unroll
    for (int i = 0; i < 16; ++i) {
        int e = e0 + i * 256 + t;
        if (e < E_EDGES) atomicAdd(&hist[dst[e] >> 8], 1);
    }
    __syncthreads();
    for (int b = t; b < NBUK; b += 256)
        if (hist[b]) atomicAdd(&bsize[b], hist[b]);
}

__global__ __launch_bounds__(512) void bscan_kernel(const int* __restrict__ bsize,
                                                    int* __restrict__ bbase,
                                                    int* __restrict__ bcursor) {
    __shared__ int sh[512];
    int t = threadIdx.x;
    sh[t] = (t < NBUK) ? bsize[t] : 0;
    __syncthreads();
#pragma unroll
    for (int off = 1; off < 512; off <<= 1) {
        int u = (t >= off) ? sh[t - off] : 0;
        __syncthreads();
        sh[t] += u;
        __syncthreads();
    }
    if (t < NBUK) {
        int ex = (t == 0) ? 0 : sh[t - 1];
        bbase[t] = ex;
        bcursor[t] = ex;
    }
    if (t == 0) bbase[NBUK] = E_EDGES;
}

__global__ __launch_bounds__(256) void bucket_scatter_kernel(const int* __restrict__ src,
                                                             const int* __restrict__ dst,
                                                             int* __restrict__ bcursor,
                                                             int2* __restrict__ pairs) {
    __shared__ int hist[NBUK];
    __shared__ int base[NBUK];
    const int t = threadIdx.x;
    for (int b = t; b < NBUK; b += 256) hist[b] = 0;
    __syncthreads();

    const int e0 = blockIdx.x * EPB;
    int s[16], d[16];
#pragma unroll
    for (int i = 0; i < 16; ++i) {
        int e = e0 + i * 256 + t;
        if (e < E_EDGES) {
            s[i] = src[e];
            d[i] = dst[e];
            atomicAdd(&hist[d[i] >> 8], 1);
        } else {
            d[i] = -1;
        }
    }
    __syncthreads();
    for (int b = t; b < NBUK; b += 256) {
        int c = hist[b];
        base[b] = c ? atomicAdd(&bcursor[b], c) : 0;
        hist[b] = 0;  // reuse as rank counter
    }
    __syncthreads();
#pragma unroll
    for (int i = 0; i < 16; ++i) {
        if (d[i] >= 0) {
            int b = d[i] >> 8;
            int r = atomicAdd(&hist[b], 1);
            pairs[base[b] + r] = make_int2(s[i], d[i]);
        }
    }
}

// One block per bucket: LDS-count nodes, emit dis + row_ptr, counting-sort csr.
__global__ __launch_bounds__(256) void bucket_sort_kernel(const int2* __restrict__ pairs,
                                                          const int* __restrict__ bbase,
                                                          int* __restrict__ row_ptr,
                                                          float* __restrict__ dis,
                                                          int* __restrict__ csr_src) {
    __shared__ int cnt[256];
    __shared__ int sh[256];
    __shared__ int cur[256];
    const int b = blockIdx.x;
    const int node0 = b << 8;
    const int t = threadIdx.x;
    const int nn = min(256, N_NODES - node0);
    const int beg = bbase[b], end = bbase[b + 1];
    cnt[t] = 0;
    __syncthreads();
    for (int e = beg + t; e < end; e += 256)
        atomicAdd(&cnt[pairs[e].y - node0], 1);
    __syncthreads();
    int c = cnt[t];
    if (t < nn) dis[node0 + t] = rsqrtf((float)c + 1.0f);
    sh[t] = c;
    __syncthreads();
#pragma unroll
    for (int off = 1; off < 256; off <<= 1) {
        int u = (t >= off) ? sh[t - off] : 0;
        __syncthreads();
        sh[t] += u;
        __syncthreads();
    }
    int start = beg + sh[t] - c;   // exclusive prefix
    if (t < nn) row_ptr[node0 + t] = start;
    cur[t] = start;
    if (b == NBUK - 1 && t == 0) row_ptr[N_NODES] = E_EDGES;
    __syncthreads();
    for (int e = beg + t; e < end; e += 256) {
        int2 p = pairs[e];
        int j = atomicAdd(&cur[p.y - node0], 1);
        csr_src[j] = p.x;
    }
}

// ---------------------------------------------------------------------------
// Weight prep: Wt[n][k] bf16 hi/lo splits for both layers (one-time, tiny)
// ---------------------------------------------------------------------------
__global__ __launch_bounds__(256) void wprep_kernel(const float* __restrict__ W1,
                                                    const float* __restrict__ W2,
                                                    short* __restrict__ w1h,
                                                    short* __restrict__ w1l,
                                                    short* __restrict__ w2h,
                                                    short* __restrict__ w2l) {
    int idx = blockIdx.x * 256 + threadIdx.x;
    if (idx < H_DIM * F_IN) {                    // W1t[n=128][k=256]
        int n = idx >> 8, k = idx & 255;
        float w = W1[k * H_DIM + n];
        bf16_t h = f2bf(w);
        w1h[idx] = (short)h;
        w1l[idx] = (short)f2bf(w - bf2f(h));
    }
    int i2 = idx - H_DIM * F_IN;
    if (i2 >= 0 && i2 < C_DIM * H_DIM) {         // W2t[n=64][k=128]
        int n = i2 >> 7, k = i2 & 127;
        float w = W2[k * C_DIM + n];
        bf16_t h = f2bf(w);
        w2h[i2] = (short)h;
        w2l[i2] = (short)f2bf(w - bf2f(h));
    }
}

// ---------------------------------------------------------------------------
// GEMM1 (MFMA): T[N,128] = dis[row] * (X[N,256] @ W1), split-bf16 3-term.
// v6: 64-row blocks (grid 1563 = 6.1 blocks/CU -> ~24 waves/CU occupancy cap,
// was 782 blocks = 3 waves/SIMD = the 20% occupancy wall). Each wave owns one
// 16-row tile, acc[8] (one mt). A direct global->register, B staged via LDS.
// B traffic doubles but is L2-served; X traffic unchanged. MFMA term order
// per output element unchanged -> bit-identical results.
// ---------------------------------------------------------------------------
#define LSTR 40
__global__ __launch_bounds__(256, 4) void gemm1_mfma(const float* __restrict__ X,
                                                     const short* __restrict__ Wth,
                                                     const short* __restrict__ Wtl,
                                                     const float* __restrict__ dis,
                                                     bf16_t* __restrict__ T,
                                                     int nrows) {
    __shared__ short Bh[128 * LSTR], Bl[128 * LSTR];
    const int t = threadIdx.x;
    const int row0 = blockIdx.x * 64;
    const int w = t >> 6;                    // 4 waves x 16 rows = 64 rows
    const int lane = t & 63;
    const int m = lane & 15;
    const int q = lane >> 4;
    const int koff = q * 8;

    const int r0 = row0 + w * 16 + m;
    const bool ok0 = r0 < nrows;
    const float* X0 = X + (long long)r0 * F_IN + q * 8;

    float4v acc[8];
#pragma unroll
    for (int j = 0; j < 8; ++j) acc[j] = {0.f, 0.f, 0.f, 0.f};

#pragma unroll 2
    for (int ks = 0; ks < 8; ++ks) {
        const int k0 = ks * 32;
        // --- B stage: cooperative coalesced load -> LDS (16 full lines/instr)
#pragma unroll
        for (int i = 0; i < 2; ++i) {
            int c = t + i * 256;
            int n = c >> 2, kc = c & 3;
            *(short8*)&Bh[n * LSTR + kc * 8] = *(const short8*)&Wth[n * F_IN + k0 + kc * 8];
            *(short8*)&Bl[n * LSTR + kc * 8] = *(const short8*)&Wtl[n * F_IN + k0 + kc * 8];
        }
        // --- A direct to registers (independent of LDS; overlaps barrier wait)
        float a0[8] = {0.f, 0.f, 0.f, 0.f, 0.f, 0.f, 0.f, 0.f};
        if (ok0) {
            *(float4*)&a0[0] = *(const float4*)&X0[k0];
            *(float4*)&a0[4] = *(const float4*)&X0[k0 + 4];
        }
        short8 ah0, al0;
        split8(a0, (short*)&ah0, (short*)&al0);
        __syncthreads();
#pragma unroll
        for (int nc = 0; nc < 8; ++nc) {
            short8 bh = *(const short8*)&Bh[(nc * 16 + m) * LSTR + koff];
            short8 bl = *(const short8*)&Bl[(nc * 16 + m) * LSTR + koff];
            acc[nc] = mfma16(ah0, bh, acc[nc]);
            acc[nc] = mfma16(al0, bh, acc[nc]);
            acc[nc] = mfma16(ah0, bl, acc[nc]);
        }
        __syncthreads();
    }
    // dis prescale per output row (4 distinct rows per thread)
    float ds[4];
#pragma unroll
    for (int reg = 0; reg < 4; ++reg) {
        int grow = row0 + w * 16 + q * 4 + reg;
        ds[reg] = (grow < nrows) ? dis[grow] : 0.f;
    }
#pragma unroll
    for (int nc = 0; nc < 8; ++nc)
#pragma unroll
        for (int reg = 0; reg < 4; ++reg) {
            int grow = row0 + w * 16 + q * 4 + reg;
            int gcol = nc * 16 + m;
            if (grow < nrows)
                T[(long long)grow * H_DIM + gcol] = f2bf(acc[nc][reg] * ds[reg]);
        }
}

// ---------------------------------------------------------------------------
// GEMM2 (MFMA): T2[N,64] = dis[row] * (relu(AGG1[N,128]+b1) @ W2)
// v6: 64-row blocks, one 16-row tile per wave, acc[4].
// ---------------------------------------------------------------------------
__global__ __launch_bounds__(256, 4) void gemm2_mfma(const float* __restrict__ A,
                                                     const float* __restrict__ b1,
                                                     const short* __restrict__ Wth,
                                                     const short* __restrict__ Wtl,
                                                     const float* __restrict__ dis,
                                                     bf16_t* __restrict__ T,
                                                     int nrows) {
    __shared__ short Bh[64 * LSTR], Bl[64 * LSTR];
    const int t = threadIdx.x;
    const int row0 = blockIdx.x * 64;
    const int w = t >> 6;
    const int lane = t & 63;
    const int m = lane & 15;
    const int q = lane >> 4;
    const int koff = q * 8;

    const int r0 = row0 + w * 16 + m;
    const bool ok0 = r0 < nrows;
    const float* A0 = A + (long long)r0 * H_DIM + q * 8;
    const float* bp = b1 + q * 8;

    float4v acc[4];
#pragma unroll
    for (int j = 0; j < 4; ++j) acc[j] = {0.f, 0.f, 0.f, 0.f};

#pragma unroll 2
    for (int ks = 0; ks < 4; ++ks) {
        const int k0 = ks * 32;
        // --- B stage (64x32 hi/lo = 256 short8 slots, one per thread)
        {
            int n = t >> 2, kc = t & 3;
            *(short8*)&Bh[n * LSTR + kc * 8] = *(const short8*)&Wth[n * H_DIM + k0 + kc * 8];
            *(short8*)&Bl[n * LSTR + kc * 8] = *(const short8*)&Wtl[n * H_DIM + k0 + kc * 8];
        }
        // --- A direct with fused bias+relu
        float4 bv0 = *(const float4*)&bp[k0];
        float4 bv1 = *(const float4*)&bp[k0 + 4];
        float a0[8] = {0.f, 0.f, 0.f, 0.f, 0.f, 0.f, 0.f, 0.f};
        if (ok0) {
            float4 v0 = *(const float4*)&A0[k0];
            float4 v1 = *(const float4*)&A0[k0 + 4];
            a0[0] = fmaxf(v0.x + bv0.x, 0.f); a0[1] = fmaxf(v0.y + bv0.y, 0.f);
            a0[2] = fmaxf(v0.z + bv0.z, 0.f); a0[3] = fmaxf(v0.w + bv0.w, 0.f);
            a0[4] = fmaxf(v1.x + bv1.x, 0.f); a0[5] = fmaxf(v1.y + bv1.y, 0.f);
            a0[6] = fmaxf(v1.z + bv1.z, 0.f); a0[7] = fmaxf(v1.w + bv1.w, 0.f);
        }
        short8 ah0, al0;
        split8(a0, (short*)&ah0, (short*)&al0);
        __syncthreads();
#pragma unroll
        for (int nc = 0; nc < 4; ++nc) {
            short8 bh = *(const short8*)&Bh[(nc * 16 + m) * LSTR + koff];
            short8 bl = *(const short8*)&Bl[(nc * 16 + m) * LSTR + koff];
            acc[nc] = mfma16(ah0, bh, acc[nc]);
            acc[nc] = mfma16(al0, bh, acc[nc]);
            acc[nc] = mfma16(ah0, bl, acc[nc]);
        }
        __syncthreads();
    }
    float ds[4];
#pragma unroll
    for (int reg = 0; reg < 4; ++reg) {
        int grow = row0 + w * 16 + q * 4 + reg;
        ds[reg] = (grow < nrows) ? dis[grow] : 0.f;
    }
#pragma unroll
    for (int nc = 0; nc < 4; ++nc)
#pragma unroll
        for (int reg = 0; reg < 4; ++reg) {
            int grow = row0 + w * 16 + q * 4 + reg;
            int gcol = nc * 16 + m;
            if (grow < nrows)
                T[(long long)grow * C_DIM + gcol] = f2bf(acc[nc][reg] * ds[reg]);
        }
}

// ---------------------------------------------------------------------------
// Aggregation v3: t rows are dis-prescaled, so aggregation is a pure row-sum:
//   out[n] = dis[n] * (t'[n] + sum_{s in N(n)} t'[s])   (+ bias)
// No per-edge dis gathers; thread = (node, 16B chunk q).
// ---------------------------------------------------------------------------
__device__ inline void add8_bf16(float* acc, uint4 u) {
#pragma unroll
    for (int p = 0; p < 4; ++p) {
        unsigned w = (&u.x)[p];
        acc[2 * p]     += __uint_as_float(w << 16);
        acc[2 * p + 1] += __uint_as_float(w & 0xffff0000u);
    }
}

template <int CS, bool HAS_BIAS, bool F16OUT>
__global__ __launch_bounds__(256) void agg_kernel(const bf16_t* __restrict__ t,
                                                  const float* __restrict__ dis,
                                                  const int* __restrict__ row_ptr,
                                                  const int* __restrict__ csr_src,
                                                  const float* __restrict__ bias,
                                                  float* __restrict__ aggf,
                                                  _Float16* __restrict__ aggh) {
    unsigned idx = blockIdx.x * 256u + threadIdx.x;
    if (idx >= (unsigned)(N_NODES << CS)) return;
    int node = idx >> CS;
    int q = idx & ((1 << CS) - 1);
    const uint4* tv = (const uint4*)t;
    int beg = row_ptr[node], end = row_ptr[node + 1];

    float acc[8];
    {   // self-loop term (coefficient 1; dis[n] applied at the end)
        uint4 u = tv[idx];
#pragma unroll
        for (int p = 0; p < 4; ++p) {
            unsigned w = (&u.x)[p];
            acc[2 * p]     = __uint_as_float(w << 16);
            acc[2 * p + 1] = __uint_as_float(w & 0xffff0000u);
        }
    }

    int j = beg;
    for (; j + 3 < end; j += 4) {
        int s0 = csr_src[j + 0], s1 = csr_src[j + 1];
        int s2 = csr_src[j + 2], s3 = csr_src[j + 3];
        uint4 u0 = tv[((unsigned)s0 << CS) + q];
        uint4 u1 = tv[((unsigned)s1 << CS) + q];
        uint4 u2 = tv[((unsigned)s2 << CS) + q];
        uint4 u3 = tv[((unsigned)s3 << CS) + q];
        add8_bf16(acc, u0);
        add8_bf16(acc, u1);
        add8_bf16(acc, u2);
        add8_bf16(acc, u3);
    }
    for (; j < end; ++j) {
        int s = csr_src[j];
        add8_bf16(acc, tv[((unsigned)s << CS) + q]);
    }

    float dd = dis[node];
#pragma unroll
    for (int p = 0; p < 8; ++p) acc[p] *= dd;

    if (HAS_BIAS) {
        float4 bv0 = ((const float4*)bias)[q * 2];
        float4 bv1 = ((const float4*)bias)[q * 2 + 1];
        acc[0] += bv0.x; acc[1] += bv0.y; acc[2] += bv0.z; acc[3] += bv0.w;
        acc[4] += bv1.x; acc[5] += bv1.y; acc[6] += bv1.z; acc[7] += bv1.w;
    }
    if (F16OUT) {
        half8v hv;
#pragma unroll
        for (int p = 0; p < 8; ++p) hv[p] = (_Float16)acc[p];
        ((half8v*)aggh)[idx] = hv;
    } else {
        float4 o0 = make_float4(acc[0], acc[1], acc[2], acc[3]);
        float4 o1 = make_float4(acc[4], acc[5], acc[6], acc[7]);
        ((float4*)aggf)[idx * 2]     = o0;
        ((float4*)aggf)[idx * 2 + 1] = o1;
    }
}

// ---------------------------------------------------------------------------
// Scoring over fp16 h2 rows (128 B): 8 lanes/edge, width-8 reduce
// ---------------------------------------------------------------------------
__global__ __launch_bounds__(256) void score_kernel(const _Float16* __restrict__ h2,
                                                    const int* __restrict__ pos,
                                                    const int* __restrict__ neg,
                                                    float* __restrict__ out) {
    int tid = blockIdx.x * 256 + threadIdx.x;
    int e = tid >> 3;
    int q = tid & 7;
    if (e >= 2 * EP_EDGES) return;
    int i, j;
    if (e < EP_EDGES) {
        j = pos[e];
        i = pos[EP_EDGES + e];
    } else {
        j = neg[e - EP_EDGES];
        i = neg[e];
    }
    half8v a = ((const half8v*)h2)[i * 8 + q];
    half8v b = ((const half8v*)h2)[j * 8 + q];
    float v = 0.f;
#pragma unroll
    for (int k = 0; k < 8; ++k) v = fmaf((float)a[k], (float)b[k], v);
    v += __shfl_down(v, 4, 8);
    v += __shfl_down(v, 2, 8);
    v += __shfl_down(v, 1, 8);
    if (q == 0) out[e] = v;
}

// ---------------------------------------------------------------------------
extern "C" void kernel_launch(void* const* d_in, const int* in_sizes, int n_in,
                              void* d_out, int out_size, void* d_ws, size_t ws_size,
                              hipStream_t stream) {
    const float* x  = (const float*)d_in[0];
    const int* pos  = (const int*)d_in[2];
    const int* neg  = (const int*)d_in[3];
    const int* ei   = (const int*)d_in[4];
    const float* W1 = (const float*)d_in[5];
    const float* b1 = (const float*)d_in[6];
    const float* W2 = (const float*)d_in[7];
    const float* b2 = (const float*)d_in[8];
    float* out = (float*)d_out;

    char* ws = (char*)d_ws;
    float*  dis     = (float*) (ws + 0);          //   400,000 B
    int*    row_ptr = (int*)   (ws + 400000);     //   400,004 B
    int*    bsize   = (int*)   (ws + 800128);     //     1,564 B
    int*    bbase   = (int*)   (ws + 801792);     //     1,568 B
    int*    bcursor = (int*)   (ws + 803456);     //     1,564 B
    int*    csr_src = (int*)   (ws + 805120);     // 6,400,000 B
    int2*   pairs   = (int2*)  (ws + 7205120);    // 12,800,000 B (CSR build only)
    _Float16* h2f16 = (_Float16*)(ws + 7205120);  // 12,800,000 B (aliases pairs; used after CSR)
    bf16_t* t       = (bf16_t*)(ws + 20005120);   // 25,600,000 B (N*128 bf16)
    float*  agg     = (float*) (ws + 45605120);   // 51,200,000 B (N*128 fp32)
    short*  w1th    = (short*) (ws + 96805120);   // 65,536 B
    short*  w1tl    = (short*) (ws + 96870656);   // 65,536 B
    short*  w2th    = (short*) (ws + 96936192);   // 16,384 B
    short*  w2tl    = (short*) (ws + 96952576);   // 16,384 B -> end 96,968,960

    const int* esrc = ei;
    const int* edst = ei + E_EDGES;

    // ---- CSR build v2 (bucketed; produces row_ptr, dis, csr_src) ----
    hipMemsetAsync(bsize, 0, NBUK * sizeof(int), stream);
    bhist_kernel<<<(E_EDGES + EPB - 1) / EPB, 256, 0, stream>>>(edst, bsize);
    bscan_kernel<<<1, 512, 0, stream>>>(bsize, bbase, bcursor);
    bucket_scatter_kernel<<<(E_EDGES + EPB - 1) / EPB, 256, 0, stream>>>(
        esrc, edst, bcursor, pairs);
    bucket_sort_kernel<<<NBUK, 256, 0, stream>>>(pairs, bbase, row_ptr, dis, csr_src);
    wprep_kernel<<<(H_DIM * F_IN + C_DIM * H_DIM + 255) / 256, 256, 0, stream>>>(
        W1, W2, w1th, w1tl, w2th, w2tl);

    // ---- layer 1 (t rows dis-prescaled) ----
    gemm1_mfma<<<(N_NODES + 63) / 64, 256, 0, stream>>>(x, w1th, w1tl, dis, t, N_NODES);
    agg_kernel<4, false, false><<<(N_NODES * 16 + 255) / 256, 256, 0, stream>>>(
        t, dis, row_ptr, csr_src, nullptr, agg, nullptr);

    // ---- layer 2 (h2 written as fp16 for scoring) ----
    gemm2_mfma<<<(N_NODES + 63) / 64, 256, 0, stream>>>(agg, b1, w2th, w2tl, dis, t, N_NODES);
    agg_kernel<3, true, true><<<(N_NODES * 8 + 255) / 256, 256, 0, stream>>>(
        t, dis, row_ptr, csr_src, b2, nullptr, h2f16);

    // ---- scoring (8 lanes/edge over 128B fp16 rows) ----
    score_kernel<<<(2 * EP_EDGES * 8) / 256, 256, 0, stream>>>(h2f16, pos, neg, out);

    // second output: zeros [2, 2*EP]
    hipMemsetAsync(out + 2 * EP_EDGES, 0, (size_t)4 * EP_EDGES * sizeof(float), stream);
}

// Round 5
// 400.295 us; speedup vs baseline: 1.0193x; 1.0193x over previous
//
#include <hip/hip_runtime.h>

#define N_NODES 100000
#define F_IN    256
#define H_DIM   128
#define C_DIM   64
#define E_EDGES 1600000
#define EP_EDGES 500000

#define NBUK 391          // buckets of 256 nodes: bucket = dst >> 8
#define EPB  4096         // edges per bucket-pass block

typedef unsigned short bf16_t;
typedef short  short8  __attribute__((ext_vector_type(8)));
typedef float  float4v __attribute__((ext_vector_type(4)));
typedef _Float16 half8v __attribute__((ext_vector_type(8)));

__device__ inline bf16_t f2bf(float f) {          // round-to-nearest-even
    unsigned u = __float_as_uint(f);
    u += 0x7fff + ((u >> 16) & 1);
    return (bf16_t)(u >> 16);
}
__device__ inline float bf2f(bf16_t h) {
    return __uint_as_float(((unsigned)h) << 16);
}
__device__ inline void split8(const float* vv, short* h, short* l) {
#pragma unroll
    for (int j = 0; j < 8; ++j) {
        bf16_t hb = f2bf(vv[j]);
        h[j] = (short)hb;
        l[j] = (short)f2bf(vv[j] - bf2f(hb));
    }
}
__device__ inline float4v mfma16(short8 a, short8 b, float4v c) {
    return __builtin_amdgcn_mfma_f32_16x16x32_bf16(a, b, c, 0, 0, 0);
}
// async global->LDS, 16B per lane; LDS dest = wave-uniform base + lane*16
__device__ inline void gload_lds16(const void* gptr, void* lptr) {
    __builtin_amdgcn_global_load_lds(
        (const __attribute__((address_space(1))) unsigned int*)gptr,
        (__attribute__((address_space(3))) unsigned int*)lptr, 16, 0, 0);
}
// k-chunk swizzle: LDS slot kc holds actual k-chunk (kc ^ ((n>>1)&3)).
// Baked into wprep's global layout so linear global_load_lds lands it right.
#define XSWZ(nn) (((nn) >> 1) & 3)

// ---------------------------------------------------------------------------
// CSR build v2: bucket hist -> bucket scan -> bucket scatter -> bucket sort
// ---------------------------------------------------------------------------
__global__ __launch_bounds__(256) void bhist_kernel(const int* __restrict__ dst,
                                                    int* __restrict__ bsize) {
    __shared__ int hist[NBUK];
    const int t = threadIdx.x;
    for (int b = t; b < NBUK; b += 256) hist[b] = 0;
    __syncthreads();
    const int e0 = blockIdx.x * EPB;
#pragma unroll
    for (int i = 0; i < 16; ++i) {
        int e = e0 + i * 256 + t;
        if (e < E_EDGES) atomicAdd(&hist[dst[e] >> 8], 1);
    }
    __syncthreads();
    for (int b = t; b < NBUK; b += 256)
        if (hist[b]) atomicAdd(&bsize[b], hist[b]);
}

__global__ __launch_bounds__(512) void bscan_kernel(const int* __restrict__ bsize,
                                                    int* __restrict__ bbase,
                                                    int* __restrict__ bcursor) {
    __shared__ int sh[512];
    int t = threadIdx.x;
    sh[t] = (t < NBUK) ? bsize[t] : 0;
    __syncthreads();
#pragma unroll
    for (int off = 1; off < 512; off <<= 1) {
        int u = (t >= off) ? sh[t - off] : 0;
        __syncthreads();
        sh[t] += u;
        __syncthreads();
    }
    if (t < NBUK) {
        int ex = (t == 0) ? 0 : sh[t - 1];
        bbase[t] = ex;
        bcursor[t] = ex;
    }
    if (t == 0) bbase[NBUK] = E_EDGES;
}

__global__ __launch_bounds__(256) void bucket_scatter_kernel(const int* __restrict__ src,
                                                             const int* __restrict__ dst,
                                                             int* __restrict__ bcursor,
                                                             int2* __restrict__ pairs) {
    __shared__ int hist[NBUK];
    __shared__ int base[NBUK];
    const int t = threadIdx.x;
    for (int b = t; b < NBUK; b += 256) hist[b] = 0;
    __syncthreads();

    const int e0 = blockIdx.x * EPB;
    int s[16], d[16];
#pragma unroll
    for (int i = 0; i < 16; ++i) {
        int e = e0 + i * 256 + t;
        if (e < E_EDGES) {
            s[i] = src[e];
            d[i] = dst[e];
            atomicAdd(&hist[d[i] >> 8], 1);
        } else {
            d[i] = -1;
        }
    }
    __syncthreads();
    for (int b = t; b < NBUK; b += 256) {
        int c = hist[b];
        base[b] = c ? atomicAdd(&bcursor[b], c) : 0;
        hist[b] = 0;  // reuse as rank counter
    }
    __syncthreads();
#pragma unroll
    for (int i = 0; i < 16; ++i) {
        if (d[i] >= 0) {
            int b = d[i] >> 8;
            int r = atomicAdd(&hist[b], 1);
            pairs[base[b] + r] = make_int2(s[i], d[i]);
        }
    }
}

// One block per bucket: LDS-count nodes, emit dis + row_ptr, counting-sort csr.
__global__ __launch_bounds__(256) void bucket_sort_kernel(const int2* __restrict__ pairs,
                                                          const int* __restrict__ bbase,
                                                          int* __restrict__ row_ptr,
                                                          float* __restrict__ dis,
                                                          int* __restrict__ csr_src) {
    __shared__ int cnt[256];
    __shared__ int sh[256];
    __shared__ int cur[256];
    const int b = blockIdx.x;
    const int node0 = b << 8;
    const int t = threadIdx.x;
    const int nn = min(256, N_NODES - node0);
    const int beg = bbase[b], end = bbase[b + 1];
    cnt[t] = 0;
    __syncthreads();
    for (int e = beg + t; e < end; e += 256)
        atomicAdd(&cnt[pairs[e].y - node0], 1);
    __syncthreads();
    int c = cnt[t];
    if (t < nn) dis[node0 + t] = rsqrtf((float)c + 1.0f);
    sh[t] = c;
    __syncthreads();
#pragma unroll
    for (int off = 1; off < 256; off <<= 1) {
        int u = (t >= off) ? sh[t - off] : 0;
        __syncthreads();
        sh[t] += u;
        __syncthreads();
    }
    int start = beg + sh[t] - c;   // exclusive prefix
    if (t < nn) row_ptr[node0 + t] = start;
    cur[t] = start;
    if (b == NBUK - 1 && t == 0) row_ptr[N_NODES] = E_EDGES;
    __syncthreads();
    for (int e = beg + t; e < end; e += 256) {
        int2 p = pairs[e];
        int j = atomicAdd(&cur[p.y - node0], 1);
        csr_src[j] = p.x;
    }
}

// ---------------------------------------------------------------------------
// Weight prep: Wt[n][k] bf16 hi/lo splits, k-chunk XOR-swizzled per n so the
// gemm's linear global_load_lds staging yields bank-conflict-free ds_reads.
// ---------------------------------------------------------------------------
__global__ __launch_bounds__(256) void wprep_kernel(const float* __restrict__ W1,
                                                    const float* __restrict__ W2,
                                                    short* __restrict__ w1h,
                                                    short* __restrict__ w1l,
                                                    short* __restrict__ w2h,
                                                    short* __restrict__ w2l) {
    int idx = blockIdx.x * 256 + threadIdx.x;
    if (idx < H_DIM * F_IN) {                    // W1t[n=128][k=256]
        int n = idx >> 8, k = idx & 255;
        int kc = (k >> 3) & 3;
        int dk = (k & ~0x18) | (((kc ^ XSWZ(n)) & 3) << 3);
        float w = W1[k * H_DIM + n];
        bf16_t h = f2bf(w);
        w1h[n * F_IN + dk] = (short)h;
        w1l[n * F_IN + dk] = (short)f2bf(w - bf2f(h));
    }
    int i2 = idx - H_DIM * F_IN;
    if (i2 >= 0 && i2 < C_DIM * H_DIM) {         // W2t[n=64][k=128]
        int n = i2 >> 7, k = i2 & 127;
        int kc = (k >> 3) & 3;
        int dk = (k & ~0x18) | (((kc ^ XSWZ(n)) & 3) << 3);
        float w = W2[k * C_DIM + n];
        bf16_t h = f2bf(w);
        w2h[n * H_DIM + dk] = (short)h;
        w2l[n * H_DIM + dk] = (short)f2bf(w - bf2f(h));
    }
}

// ---------------------------------------------------------------------------
// GEMM1 (MFMA): T[N,128] = dis[row] * (X[N,256] @ W1), split-bf16 3-term.
// v7: 128-row blocks (2 mt/wave), B staged via global_load_lds into a
// double-buffered unpadded [128][32] LDS tile (swizzled source => conflict-free
// reads), ONE barrier per ks. A direct global->register, prefetched one ks
// ahead. MFMA order identical -> bit-identical output.
// ---------------------------------------------------------------------------
#define G1_STAGE(BUF, KSN)                                                     \
    for (int i_ = 0; i_ < 2; ++i_) {                                           \
        int e_ = t + i_ * 256;                                                 \
        gload_lds16(&Wth[(e_ >> 2) * F_IN + (KSN) * 32 + (e_ & 3) * 8],        \
                    &Bh[(BUF) * 4096 + e_ * 8]);                               \
        gload_lds16(&Wtl[(e_ >> 2) * F_IN + (KSN) * 32 + (e_ & 3) * 8],        \
                    &Bl[(BUF) * 4096 + e_ * 8]);                               \
    }

#define G1_LOADA(BANK, KSN)                                                    \
    if (ok0) {                                                                 \
        *(float4*)&aP[BANK][0][0] = *(const float4*)&X0[(KSN) * 32];           \
        *(float4*)&aP[BANK][0][4] = *(const float4*)&X0[(KSN) * 32 + 4];       \
    }                                                                          \
    if (ok1) {                                                                 \
        *(float4*)&aP[BANK][1][0] = *(const float4*)&X1[(KSN) * 32];           \
        *(float4*)&aP[BANK][1][4] = *(const float4*)&X1[(KSN) * 32 + 4];       \
    }

__global__ __launch_bounds__(256, 3) void gemm1_mfma(const float* __restrict__ X,
                                                     const short* __restrict__ Wth,
                                                     const short* __restrict__ Wtl,
                                                     const float* __restrict__ dis,
                                                     bf16_t* __restrict__ T,
                                                     int nrows) {
    __shared__ short Bh[2 * 4096], Bl[2 * 4096];   // 2 bufs x [128][32], 32 KB
    const int t = threadIdx.x;
    const int row0 = blockIdx.x * 128;
    const int w = t >> 6;
    const int lane = t & 63;
    const int m = lane & 15;
    const int q = lane >> 4;
    const int qs = ((q ^ XSWZ(m)) & 3) << 3;       // swizzled 8-short slot

    const int r0 = row0 + w * 32 + m;
    const int r1 = r0 + 16;
    const bool ok0 = r0 < nrows;
    const bool ok1 = r1 < nrows;
    const float* X0 = X + (long long)r0 * F_IN + q * 8;
    const float* X1 = X + (long long)r1 * F_IN + q * 8;

    float4v acc[2][8];
#pragma unroll
    for (int i = 0; i < 2; ++i)
#pragma unroll
        for (int j = 0; j < 8; ++j) acc[i][j] = {0.f, 0.f, 0.f, 0.f};

    float aP[2][2][8] = {};

    // prologue: stage ks=0 into buf0, A(0) into bank0
    G1_STAGE(0, 0)
    G1_LOADA(0, 0)
    __syncthreads();

#pragma unroll
    for (int ks = 0; ks < 8; ++ks) {
        const int p = ks & 1;
        if (ks < 7) {
            G1_STAGE(p ^ 1, ks + 1)      // loads fly under this phase's compute
            G1_LOADA(p ^ 1, ks + 1)
        }
        short8 ah0, al0, ah1, al1;
        split8(aP[p][0], (short*)&ah0, (short*)&al0);
        split8(aP[p][1], (short*)&ah1, (short*)&al1);
#pragma unroll
        for (int nc = 0; nc < 8; ++nc) {
            const int bo = p * 4096 + (nc * 16 + m) * 32 + qs;
            short8 bh = *(const short8*)&Bh[bo];
            short8 bl = *(const short8*)&Bl[bo];
            acc[0][nc] = mfma16(ah0, bh, acc[0][nc]);
            acc[0][nc] = mfma16(al0, bh, acc[0][nc]);
            acc[0][nc] = mfma16(ah0, bl, acc[0][nc]);
            acc[1][nc] = mfma16(ah1, bh, acc[1][nc]);
            acc[1][nc] = mfma16(al1, bh, acc[1][nc]);
            acc[1][nc] = mfma16(ah1, bl, acc[1][nc]);
        }
        __syncthreads();                 // drains vmcnt -> next buf ready
    }
    // dis prescale per output row
    float ds_[2][4];
#pragma unroll
    for (int mt = 0; mt < 2; ++mt)
#pragma unroll
        for (int reg = 0; reg < 4; ++reg) {
            int grow = row0 + w * 32 + mt * 16 + q * 4 + reg;
            ds_[mt][reg] = (grow < nrows) ? dis[grow] : 0.f;
        }
#pragma unroll
    for (int mt = 0; mt < 2; ++mt)
#pragma unroll
        for (int nc = 0; nc < 8; ++nc)
#pragma unroll
            for (int reg = 0; reg < 4; ++reg) {
                int grow = row0 + w * 32 + mt * 16 + q * 4 + reg;
                int gcol = nc * 16 + m;
                if (grow < nrows)
                    T[(long long)grow * H_DIM + gcol] = f2bf(acc[mt][nc][reg] * ds_[mt][reg]);
            }
}

// ---------------------------------------------------------------------------
// GEMM2 (MFMA): T2[N,64] = dis[row] * (relu(AGG1[N,128]+b1) @ W2)
// v7: same dbuf global_load_lds structure; 4 ks phases; 16 KB LDS.
// ---------------------------------------------------------------------------
#define G2_STAGE(BUF, KSN)                                                     \
    gload_lds16(&Wth[(t >> 2) * H_DIM + (KSN) * 32 + (t & 3) * 8],             \
                &Bh[(BUF) * 2048 + t * 8]);                                    \
    gload_lds16(&Wtl[(t >> 2) * H_DIM + (KSN) * 32 + (t & 3) * 8],             \
                &Bl[(BUF) * 2048 + t * 8]);

#define G2_LOADA(BANK, KSN)                                                    \
    if (ok0) {                                                                 \
        *(float4*)&aP[BANK][0][0] = *(const float4*)&A0[(KSN) * 32];           \
        *(float4*)&aP[BANK][0][4] = *(const float4*)&A0[(KSN) * 32 + 4];       \
    }                                                                          \
    if (ok1) {                                                                 \
        *(float4*)&aP[BANK][1][0] = *(const float4*)&A1[(KSN) * 32];           \
        *(float4*)&aP[BANK][1][4] = *(const float4*)&A1[(KSN) * 32 + 4];       \
    }

__global__ __launch_bounds__(256, 3) void gemm2_mfma(const float* __restrict__ A,
                                                     const float* __restrict__ b1,
                                                     const short* __restrict__ Wth,
                                                     const short* __restrict__ Wtl,
                                                     const float* __restrict__ dis,
                                                     bf16_t* __restrict__ T,
                                                     int nrows) {
    __shared__ short Bh[2 * 2048], Bl[2 * 2048];   // 2 bufs x [64][32], 16 KB
    const int t = threadIdx.x;
    const int row0 = blockIdx.x * 128;
    const int w = t >> 6;
    const int lane = t & 63;
    const int m = lane & 15;
    const int q = lane >> 4;
    const int qs = ((q ^ XSWZ(m)) & 3) << 3;

    const int r0 = row0 + w * 32 + m;
    const int r1 = r0 + 16;
    const bool ok0 = r0 < nrows;
    const bool ok1 = r1 < nrows;
    const float* A0 = A + (long long)r0 * H_DIM + q * 8;
    const float* A1 = A + (long long)r1 * H_DIM + q * 8;
    const float* bp = b1 + q * 8;

    float4v acc[2][4];
#pragma unroll
    for (int i = 0; i < 2; ++i)
#pragma unroll
        for (int j = 0; j < 4; ++j) acc[i][j] = {0.f, 0.f, 0.f, 0.f};

    float aP[2][2][8] = {};

    G2_STAGE(0, 0)
    G2_LOADA(0, 0)
    __syncthreads();

#pragma unroll
    for (int ks = 0; ks < 4; ++ks) {
        const int p = ks & 1;
        if (ks < 3) {
            G2_STAGE(p ^ 1, ks + 1)
            G2_LOADA(p ^ 1, ks + 1)
        }
        float4 bv0 = *(const float4*)&bp[ks * 32];
        float4 bv1 = *(const float4*)&bp[ks * 32 + 4];
        float a0[8], a1[8];
        a0[0] = fmaxf(aP[p][0][0] + bv0.x, 0.f); a0[1] = fmaxf(aP[p][0][1] + bv0.y, 0.f);
        a0[2] = fmaxf(aP[p][0][2] + bv0.z, 0.f); a0[3] = fmaxf(aP[p][0][3] + bv0.w, 0.f);
        a0[4] = fmaxf(aP[p][0][4] + bv1.x, 0.f); a0[5] = fmaxf(aP[p][0][5] + bv1.y, 0.f);
        a0[6] = fmaxf(aP[p][0][6] + bv1.z, 0.f); a0[7] = fmaxf(aP[p][0][7] + bv1.w, 0.f);
        a1[0] = fmaxf(aP[p][1][0] + bv0.x, 0.f); a1[1] = fmaxf(aP[p][1][1] + bv0.y, 0.f);
        a1[2] = fmaxf(aP[p][1][2] + bv0.z, 0.f); a1[3] = fmaxf(aP[p][1][3] + bv0.w, 0.f);
        a1[4] = fmaxf(aP[p][1][4] + bv1.x, 0.f); a1[5] = fmaxf(aP[p][1][5] + bv1.y, 0.f);
        a1[6] = fmaxf(aP[p][1][6] + bv1.z, 0.f); a1[7] = fmaxf(aP[p][1][7] + bv1.w, 0.f);
        short8 ah0, al0, ah1, al1;
        split8(a0, (short*)&ah0, (short*)&al0);
        split8(a1, (short*)&ah1, (short*)&al1);
#pragma unroll
        for (int nc = 0; nc < 4; ++nc) {
            const int bo = p * 2048 + (nc * 16 + m) * 32 + qs;
            short8 bh = *(const short8*)&Bh[bo];
            short8 bl = *(const short8*)&Bl[bo];
            acc[0][nc] = mfma16(ah0, bh, acc[0][nc]);
            acc[0][nc] = mfma16(al0, bh, acc[0][nc]);
            acc[0][nc] = mfma16(ah0, bl, acc[0][nc]);
            acc[1][nc] = mfma16(ah1, bh, acc[1][nc]);
            acc[1][nc] = mfma16(al1, bh, acc[1][nc]);
            acc[1][nc] = mfma16(ah1, bl, acc[1][nc]);
        }
        __syncthreads();
    }
    float ds_[2][4];
#pragma unroll
    for (int mt = 0; mt < 2; ++mt)
#pragma unroll
        for (int reg = 0; reg < 4; ++reg) {
            int grow = row0 + w * 32 + mt * 16 + q * 4 + reg;
            ds_[mt][reg] = (grow < nrows) ? dis[grow] : 0.f;
        }
#pragma unroll
    for (int mt = 0; mt < 2; ++mt)
#pragma unroll
        for (int nc = 0; nc < 4; ++nc)
#pragma unroll
            for (int reg = 0; reg < 4; ++reg) {
                int grow = row0 + w * 32 + mt * 16 + q * 4 + reg;
                int gcol = nc * 16 + m;
                if (grow < nrows)
                    T[(long long)grow * C_DIM + gcol] = f2bf(acc[mt][nc][reg] * ds_[mt][reg]);
            }
}

// ---------------------------------------------------------------------------
// Aggregation: t rows are dis-prescaled, so aggregation is a pure row-sum:
//   out[n] = dis[n] * (t'[n] + sum_{s in N(n)} t'[s])   (+ bias)
// ---------------------------------------------------------------------------
__device__ inline void add8_bf16(float* acc, uint4 u) {
#pragma unroll
    for (int p = 0; p < 4; ++p) {
        unsigned w = (&u.x)[p];
        acc[2 * p]     += __uint_as_float(w << 16);
        acc[2 * p + 1] += __uint_as_float(w & 0xffff0000u);
    }
}

template <int CS, bool HAS_BIAS, bool F16OUT>
__global__ __launch_bounds__(256) void agg_kernel(const bf16_t* __restrict__ t,
                                                  const float* __restrict__ dis,
                                                  const int* __restrict__ row_ptr,
                                                  const int* __restrict__ csr_src,
                                                  const float* __restrict__ bias,
                                                  float* __restrict__ aggf,
                                                  _Float16* __restrict__ aggh) {
    unsigned idx = blockIdx.x * 256u + threadIdx.x;
    if (idx >= (unsigned)(N_NODES << CS)) return;
    int node = idx >> CS;
    int q = idx & ((1 << CS) - 1);
    const uint4* tv = (const uint4*)t;
    int beg = row_ptr[node], end = row_ptr[node + 1];

    float acc[8];
    {   // self-loop term (coefficient 1; dis[n] applied at the end)
        uint4 u = tv[idx];
#pragma unroll
        for (int p = 0; p < 4; ++p) {
            unsigned w = (&u.x)[p];
            acc[2 * p]     = __uint_as_float(w << 16);
            acc[2 * p + 1] = __uint_as_float(w & 0xffff0000u);
        }
    }

    int j = beg;
    for (; j + 3 < end; j += 4) {
        int s0 = csr_src[j + 0], s1 = csr_src[j + 1];
        int s2 = csr_src[j + 2], s3 = csr_src[j + 3];
        uint4 u0 = tv[((unsigned)s0 << CS) + q];
        uint4 u1 = tv[((unsigned)s1 << CS) + q];
        uint4 u2 = tv[((unsigned)s2 << CS) + q];
        uint4 u3 = tv[((unsigned)s3 << CS) + q];
        add8_bf16(acc, u0);
        add8_bf16(acc, u1);
        add8_bf16(acc, u2);
        add8_bf16(acc, u3);
    }
    for (; j < end; ++j) {
        int s = csr_src[j];
        add8_bf16(acc, tv[((unsigned)s << CS) + q]);
    }

    float dd = dis[node];
#pragma unroll
    for (int p = 0; p < 8; ++p) acc[p] *= dd;

    if (HAS_BIAS) {
        float4 bv0 = ((const float4*)bias)[q * 2];
        float4 bv1 = ((const float4*)bias)[q * 2 + 1];
        acc[0] += bv0.x; acc[1] += bv0.y; acc[2] += bv0.z; acc[3] += bv0.w;
        acc[4] += bv1.x; acc[5] += bv1.y; acc[6] += bv1.z; acc[7] += bv1.w;
    }
    if (F16OUT) {
        half8v hv;
#pragma unroll
        for (int p = 0; p < 8; ++p) hv[p] = (_Float16)acc[p];
        ((half8v*)aggh)[idx] = hv;
    } else {
        float4 o0 = make_float4(acc[0], acc[1], acc[2], acc[3]);
        float4 o1 = make_float4(acc[4], acc[5], acc[6], acc[7]);
        ((float4*)aggf)[idx * 2]     = o0;
        ((float4*)aggf)[idx * 2 + 1] = o1;
    }
}

// ---------------------------------------------------------------------------
// Scoring over fp16 h2 rows (128 B): 8 lanes/edge, width-8 reduce
// ---------------------------------------------------------------------------
__global__ __launch_bounds__(256) void score_kernel(const _Float16* __restrict__ h2,
                                                    const int* __restrict__ pos,
                                                    const int* __restrict__ neg,
                                                    float* __restrict__ out) {
    int tid = blockIdx.x * 256 + threadIdx.x;
    int e = tid >> 3;
    int q = tid & 7;
    if (e >= 2 * EP_EDGES) return;
    int i, j;
    if (e < EP_EDGES) {
        j = pos[e];
        i = pos[EP_EDGES + e];
    } else {
        j = neg[e - EP_EDGES];
        i = neg[e];
    }
    half8v a = ((const half8v*)h2)[i * 8 + q];
    half8v b = ((const half8v*)h2)[j * 8 + q];
    float v = 0.f;
#pragma unroll
    for (int k = 0; k < 8; ++k) v = fmaf((float)a[k], (float)b[k], v);
    v += __shfl_down(v, 4, 8);
    v += __shfl_down(v, 2, 8);
    v += __shfl_down(v, 1, 8);
    if (q == 0) out[e] = v;
}

// ---------------------------------------------------------------------------
extern "C" void kernel_launch(void* const* d_in, const int* in_sizes, int n_in,
                              void* d_out, int out_size, void* d_ws, size_t ws_size,
                              hipStream_t stream) {
    const float* x  = (const float*)d_in[0];
    const int* pos  = (const int*)d_in[2];
    const int* neg  = (const int*)d_in[3];
    const int* ei   = (const int*)d_in[4];
    const float* W1 = (const float*)d_in[5];
    const float* b1 = (const float*)d_in[6];
    const float* W2 = (const float*)d_in[7];
    const float* b2 = (const float*)d_in[8];
    float* out = (float*)d_out;

    char* ws = (char*)d_ws;
    float*  dis     = (float*) (ws + 0);          //   400,000 B
    int*    row_ptr = (int*)   (ws + 400000);     //   400,004 B
    int*    bsize   = (int*)   (ws + 800128);     //     1,564 B
    int*    bbase   = (int*)   (ws + 801792);     //     1,568 B
    int*    bcursor = (int*)   (ws + 803456);     //     1,564 B
    int*    csr_src = (int*)   (ws + 805120);     // 6,400,000 B
    int2*   pairs   = (int2*)  (ws + 7205120);    // 12,800,000 B (CSR build only)
    _Float16* h2f16 = (_Float16*)(ws + 7205120);  // 12,800,000 B (aliases pairs; used after CSR)
    bf16_t* t       = (bf16_t*)(ws + 20005120);   // 25,600,000 B (N*128 bf16)
    float*  agg     = (float*) (ws + 45605120);   // 51,200,000 B (N*128 fp32)
    short*  w1th    = (short*) (ws + 96805120);   // 65,536 B
    short*  w1tl    = (short*) (ws + 96870656);   // 65,536 B
    short*  w2th    = (short*) (ws + 96936192);   // 16,384 B
    short*  w2tl    = (short*) (ws + 96952576);   // 16,384 B -> end 96,968,960

    const int* esrc = ei;
    const int* edst = ei + E_EDGES;

    // ---- CSR build v2 (bucketed; produces row_ptr, dis, csr_src) ----
    hipMemsetAsync(bsize, 0, NBUK * sizeof(int), stream);
    bhist_kernel<<<(E_EDGES + EPB - 1) / EPB, 256, 0, stream>>>(edst, bsize);
    bscan_kernel<<<1, 512, 0, stream>>>(bsize, bbase, bcursor);
    bucket_scatter_kernel<<<(E_EDGES + EPB - 1) / EPB, 256, 0, stream>>>(
        esrc, edst, bcursor, pairs);
    bucket_sort_kernel<<<NBUK, 256, 0, stream>>>(pairs, bbase, row_ptr, dis, csr_src);
    wprep_kernel<<<(H_DIM * F_IN + C_DIM * H_DIM + 255) / 256, 256, 0, stream>>>(
        W1, W2, w1th, w1tl, w2th, w2tl);

    // ---- layer 1 (t rows dis-prescaled) ----
    gemm1_mfma<<<(N_NODES + 127) / 128, 256, 0, stream>>>(x, w1th, w1tl, dis, t, N_NODES);
    agg_kernel<4, false, false><<<(N_NODES * 16 + 255) / 256, 256, 0, stream>>>(
        t, dis, row_ptr, csr_src, nullptr, agg, nullptr);

    // ---- layer 2 (h2 written as fp16 for scoring) ----
    gemm2_mfma<<<(N_NODES + 127) / 128, 256, 0, stream>>>(agg, b1, w2th, w2tl, dis, t, N_NODES);
    agg_kernel<3, true, true><<<(N_NODES * 8 + 255) / 256, 256, 0, stream>>>(
        t, dis, row_ptr, csr_src, b2, nullptr, h2f16);

    // ---- scoring (8 lanes/edge over 128B fp16 rows) ----
    score_kernel<<<(2 * EP_EDGES * 8) / 256, 256, 0, stream>>>(h2f16, pos, neg, out);

    // second output: zeros [2, 2*EP]
    hipMemsetAsync(out + 2 * EP_EDGES, 0, (size_t)4 * EP_EDGES * sizeof(float), stream);
}